// Round 5
// baseline (550.388 us; speedup 1.0000x reference)
//
#include <hip/hip_runtime.h>

// Problem constants: B=2, T=1024, C=1024, H=16, D=64, K=C=1024.
#define T_DIM 1024
#define C_DIM 1024
#define H_DIM 16
#define D_DIM 64
#define KD    1024

#define NEG_BIG (-1e30f)

typedef short  short8  __attribute__((ext_vector_type(8)));
typedef short  short4v __attribute__((ext_vector_type(4)));
typedef float  f32x4   __attribute__((ext_vector_type(4)));

__device__ __forceinline__ float bf2f(short s) {
  return __uint_as_float(((unsigned)(unsigned short)s) << 16);
}
__device__ __forceinline__ short f2bf(float f) {
  unsigned u = __float_as_uint(f);
  u += 0x7fffu + ((u >> 16) & 1u);   // round-to-nearest-even
  return (short)(u >> 16);
}
__device__ __forceinline__ unsigned pk2(float lo, float hi) {
  return ((unsigned)(unsigned short)f2bf(lo)) | (((unsigned)(unsigned short)f2bf(hi)) << 16);
}

// Load an 8-element bf16 fragment from either bf16 or fp32 source (uniform flag).
__device__ __forceinline__ short8 ldfrag(const void* p, size_t off, int isf32) {
  if (isf32) {
    const float* q = (const float*)p + off;
    f32x4 lo = *(const f32x4*)q;
    f32x4 hi = *(const f32x4*)(q + 4);
    short8 r;
#pragma unroll
    for (int j = 0; j < 4; ++j) { r[j] = f2bf(lo[j]); r[j + 4] = f2bf(hi[j]); }
    return r;
  }
  return *(const short8*)((const short*)p + off);
}
__device__ __forceinline__ float ldbias(const void* b, int i, int isf32) {
  return isf32 ? ((const float*)b)[i] : bf2f(((const short*)b)[i]);
}

// ---------------------------------------------------------------------------
// Input-dtype probe: u32 bits 7..14 = exponent field of the LOW bf16 if the
// buffer is bf16 pairs (≈[110,135] for N(0,1) data); random mantissa bits if
// the buffer is fp32. flag=1 -> inputs are fp32.
// ---------------------------------------------------------------------------
__global__ void detect_k(const unsigned* __restrict__ q, unsigned* __restrict__ flag) {
  if (threadIdx.x == 0) {
    int c = 0;
    for (int i = 0; i < 256; ++i) {
      unsigned e = (q[i] >> 7) & 0xffu;
      c += (e >= 110u && e <= 135u) ? 1 : 0;
    }
    *flag = (c < 128) ? 1u : 0u;
  }
}

// ---------------------------------------------------------------------------
// GEMM: C[m][c] = sum_k X[m][k] * W[c][k] + bias[c]   (m in [0,2048), c,k in [0,1024))
// TRANS=1: MFMA computes C^T tiles (rows=c) -> packed stores.
// MODE: 0 = plain out[m*C + c] (fp32 if OUTF32); 1 = [b,h,t,d] bf16 (q/k proj);
//       2 = [b,h,d,t] bf16 (v proj, transposed; requires TRANS=0)
// EXTX: X is an external input (dtype per flag); internal buffers always bf16.
// ---------------------------------------------------------------------------
template<int TRANS, int MODE, int EXTX, int OUTF32>
__global__ __launch_bounds__(256) void gemm_k(const void* __restrict__ Xv,
                                              const void* __restrict__ Wv,
                                              const void* __restrict__ Bv,
                                              void* __restrict__ outv,
                                              const unsigned* __restrict__ flagp)
{
  const unsigned f = flagp ? *flagp : 0u;
  const int xf = (EXTX && f) ? 1 : 0;
  const int wf = f ? 1 : 0;

  const int lane  = threadIdx.x & 63;
  const int wave  = threadIdx.x >> 6;
  const int col16 = lane & 15;
  const int quad  = lane >> 4;
  const int m0 = blockIdx.x * 256 + wave * 64;
  const int c0 = blockIdx.y * 64;

  const size_t xoff = (size_t)(m0 + col16) * KD + quad * 8;
  const size_t woff = (size_t)(c0 + col16) * KD + quad * 8;

  f32x4 acc[4][4] = {};   // [i = m-subtile][j = c-subtile]

  for (int k0 = 0; k0 < KD; k0 += 32) {
    short8 fx[4], fw[4];
#pragma unroll
    for (int i = 0; i < 4; ++i) fx[i] = ldfrag(Xv, xoff + (size_t)i * 16 * KD + k0, xf);
#pragma unroll
    for (int j = 0; j < 4; ++j) fw[j] = ldfrag(Wv, woff + (size_t)j * 16 * KD + k0, wf);
#pragma unroll
    for (int i = 0; i < 4; ++i) {
#pragma unroll
      for (int j = 0; j < 4; ++j) {
        if (TRANS)
          acc[i][j] = __builtin_amdgcn_mfma_f32_16x16x32_bf16(fw[j], fx[i], acc[i][j], 0, 0, 0);
        else
          acc[i][j] = __builtin_amdgcn_mfma_f32_16x16x32_bf16(fx[i], fw[j], acc[i][j], 0, 0, 0);
      }
    }
  }

#pragma unroll
  for (int i = 0; i < 4; ++i) {
#pragma unroll
    for (int j = 0; j < 4; ++j) {
      if (TRANS) {
        // C^T tile: lane holds col = m (n-operand = fx), rows = c (quad*4+r)
        const int m  = m0 + i * 16 + col16;
        const int cb = c0 + j * 16 + quad * 4;           // 4 consecutive c
        if (MODE == 0 && OUTF32) {
          f32x4 pv;
#pragma unroll
          for (int r = 0; r < 4; ++r) pv[r] = acc[i][j][r] + ldbias(Bv, cb + r, wf);
          *(f32x4*)((float*)outv + (size_t)m * C_DIM + cb) = pv;
        } else {
          short4v pk;
#pragma unroll
          for (int r = 0; r < 4; ++r) pk[r] = f2bf(acc[i][j][r] + ldbias(Bv, cb + r, wf));
          size_t off;
          if (MODE == 0) {
            off = (size_t)m * C_DIM + cb;
          } else {
            const int b = m >> 10, t = m & 1023, h = cb >> 6, d = cb & 63;
            off = ((size_t)(b * H_DIM + h) << 16) + (size_t)t * D_DIM + d;
          }
          *(short4v*)((short*)outv + off) = pk;
        }
      } else {
        // normal tile: lane holds col = c, rows = m (quad*4+r) -> consecutive t (MODE 2)
        const int c  = c0 + j * 16 + col16;
        const int t0 = m0 + i * 16 + quad * 4;           // 4 consecutive m(=t)
        const float bv = ldbias(Bv, c, wf);
        short4v pk;
#pragma unroll
        for (int r = 0; r < 4; ++r) pk[r] = f2bf(acc[i][j][r] + bv);
        const int b = t0 >> 10, t = t0 & 1023, h = c >> 6, d = c & 63;
        size_t off = (size_t)((b * H_DIM + h) * D_DIM + d) * T_DIM + t;
        *(short4v*)((short*)outv + off) = pk;
      }
    }
  }
}

// ---------------------------------------------------------------------------
// Causal flash attention, transposed-score formulation (validated R3/R4:
// produced bit-identical final output vs the scalar oracle).
// qp,kp: [b,h,t,d] bf16; vpt: [b,h,d,t] bf16; y out: [b,t,h*64+d] bf16.
// ---------------------------------------------------------------------------
__global__ __launch_bounds__(256) void attn_k(const short* __restrict__ qp,
                                              const short* __restrict__ kp,
                                              const short* __restrict__ vpt,
                                              short* __restrict__ y)
{
  const int lane = threadIdx.x & 63;
  const int wave = threadIdx.x >> 6;
  const int col  = lane & 15;   // q index within tile
  const int quad = lane >> 4;
  const int bh = blockIdx.y;
  const int b = bh >> 4, h = bh & 15;
  const int qblk = (int)gridDim.x - 1 - (int)blockIdx.x;  // heavy blocks first
  const int q0 = qblk * 64 + wave * 16;
  const int myq = q0 + col;

  const short* qph = qp  + (size_t)bh * (T_DIM * D_DIM);
  const short* kph = kp  + (size_t)bh * (T_DIM * D_DIM);
  const short* vph = vpt + (size_t)bh * (D_DIM * T_DIM);

  // Q fragments (B operand of S^T): B[k=d][n=q]
  short8 bQ[2];
#pragma unroll
  for (int kk = 0; kk < 2; ++kk)
    bQ[kk] = *(const short8*)(qph + (size_t)(q0 + col) * D_DIM + kk * 32 + quad * 8);

  f32x4 O[4] = {};              // O^T tiles: rows = d (quad*4+r), col = q
  float m_q = NEG_BIG, l_q = 0.0f;

  // Shuffle source lanes for the P^T -> B-operand transpose:
  const int slA = col + ((quad & 1) * 32);
  const int slB = slA + 16;

  const int ktiles = (q0 + 47) >> 5;   // keys 0 .. q0+15 needed (causal)
  for (int kt = 0; kt < ktiles; ++kt) {
    const int kb = kt * 32;
    f32x4 st[2];
#pragma unroll
    for (int jt = 0; jt < 2; ++jt) {
      f32x4 s = {0.f, 0.f, 0.f, 0.f};
      const short* kbase = kph + (size_t)(kb + jt * 16 + col) * D_DIM + quad * 8;
      short8 aK0 = *(const short8*)(kbase);
      short8 aK1 = *(const short8*)(kbase + 32);
      s = __builtin_amdgcn_mfma_f32_16x16x32_bf16(aK0, bQ[0], s, 0, 0, 0);
      s = __builtin_amdgcn_mfma_f32_16x16x32_bf16(aK1, bQ[1], s, 0, 0, 0);
      st[jt] = s;
    }
    // scale + causal mask + column(=q)-wise online softmax (all-finite math)
    float mnew = m_q;
#pragma unroll
    for (int jt = 0; jt < 2; ++jt) {
#pragma unroll
      for (int r = 0; r < 4; ++r) {
        float sv = st[jt][r] * 0.125f;        // 1/sqrt(64)
        const int key = kb + jt * 16 + quad * 4 + r;
        sv = (key > myq) ? NEG_BIG : sv;
        st[jt][r] = sv;
        mnew = fmaxf(mnew, sv);
      }
    }
    mnew = fmaxf(mnew, __shfl_xor(mnew, 16));
    mnew = fmaxf(mnew, __shfl_xor(mnew, 32));
    const float alpha = __expf(m_q - mnew);   // underflows to 0 on first tile
    m_q = mnew;
    float rs = 0.0f;
#pragma unroll
    for (int jt = 0; jt < 2; ++jt) {
#pragma unroll
      for (int r = 0; r < 4; ++r) {
        float p = __expf(st[jt][r] - mnew);   // masked: exp(-1e30) = 0
        st[jt][r] = p;
        rs += p;
      }
    }
    rs += __shfl_xor(rs, 16);
    rs += __shfl_xor(rs, 32);
    l_q = l_q * alpha + rs;
#pragma unroll
    for (int dt = 0; dt < 4; ++dt) {
#pragma unroll
      for (int r = 0; r < 4; ++r) O[dt][r] *= alpha;
    }

    // --- P^T (C-layout) -> B-operand layout via register shuffles ---
    const int a0 = (int)pk2(st[0][0], st[0][1]);
    const int a1 = (int)pk2(st[0][2], st[0][3]);
    const int b0 = (int)pk2(st[1][0], st[1][1]);
    const int b1 = (int)pk2(st[1][2], st[1][3]);
    const int tA0 = __shfl(a0, slA, 64), tB0 = __shfl(b0, slA, 64);
    const int tA1 = __shfl(a1, slA, 64), tB1 = __shfl(b1, slA, 64);
    const int tA2 = __shfl(a0, slB, 64), tB2 = __shfl(b0, slB, 64);
    const int tA3 = __shfl(a1, slB, 64), tB3 = __shfl(b1, slB, 64);
    union { unsigned u[4]; short8 s8; } uu;
    uu.u[0] = (unsigned)((quad < 2) ? tA0 : tB0);
    uu.u[1] = (unsigned)((quad < 2) ? tA1 : tB1);
    uu.u[2] = (unsigned)((quad < 2) ? tA2 : tB2);
    uu.u[3] = (unsigned)((quad < 2) ? tA3 : tB3);
    const short8 bP32 = uu.s8;

#pragma unroll
    for (int dt = 0; dt < 4; ++dt) {
      short8 aV = *(const short8*)(vph + (size_t)(dt * 16 + col) * T_DIM + kb + quad * 8);
      O[dt] = __builtin_amdgcn_mfma_f32_16x16x32_bf16(aV, bP32, O[dt], 0, 0, 0);
    }
  }

  const float rl = 1.0f / l_q;
  const int t = q0 + col;
  const size_t ybase = ((size_t)(b * T_DIM + t)) * C_DIM + h * D_DIM + quad * 4;
#pragma unroll
  for (int dt = 0; dt < 4; ++dt) {
    short4v pk;
#pragma unroll
    for (int r = 0; r < 4; ++r) pk[r] = f2bf(O[dt][r] * rl);
    *(short4v*)(y + ybase + dt * 16) = pk;
  }
}

// ---------------------------------------------------------------------------
extern "C" void kernel_launch(void* const* d_in, const int* in_sizes, int n_in,
                              void* d_out, int out_size, void* d_ws, size_t ws_size,
                              hipStream_t stream) {
  const void* q = d_in[0];
  const void* k = d_in[1];
  const void* v = d_in[2];
  // Mask input (bool [1,1,T,T]) may or may not be materialized as an input.
  int wi = (n_in >= 8 && in_sizes[4] == C_DIM * C_DIM) ? 4 : 3;
  const void* Wk = d_in[wi];
  const void* bk = d_in[wi + 1];
  const void* Wc = d_in[wi + 2];
  const void* bc = d_in[wi + 3];

  short* ws  = (short*)d_ws;
  const size_t SZ = (size_t)2 * T_DIM * C_DIM;  // 2,097,152 elements per buffer
  short* qp  = ws;
  short* kp  = ws + SZ;
  short* vpt = ws + 2 * SZ;
  short* y   = ws + 3 * SZ;

  const size_t used = 4 * SZ * sizeof(short);   // 16 MiB
  unsigned* flagp = (ws_size >= used + 64) ? (unsigned*)((char*)d_ws + used) : nullptr;
  if (flagp) detect_k<<<1, 64, 0, stream>>>((const unsigned*)q, flagp);

  dim3 blk(256);
  dim3 gg(8, 16);           // 2048/256 x 1024/64
  gemm_k<1, 1, 1, 0><<<gg, blk, 0, stream>>>(q, Wk, bk, qp, flagp);
  gemm_k<1, 1, 1, 0><<<gg, blk, 0, stream>>>(k, Wk, bk, kp, flagp);
  gemm_k<0, 2, 1, 0><<<gg, blk, 0, stream>>>(v, Wk, bk, vpt, flagp);
  attn_k<<<dim3(16, 32), blk, 0, stream>>>(qp, kp, vpt, y);
  gemm_k<1, 0, 0, 1><<<gg, blk, 0, stream>>>(y, Wc, bc, d_out, flagp);  // fp32 out
}

// Round 6
// 220.273 us; speedup vs baseline: 2.4987x; 2.4987x over previous
//
#include <hip/hip_runtime.h>

// Problem constants: B=2, T=1024, C=1024, H=16, D=64, K=C=1024.
#define T_DIM 1024
#define C_DIM 1024
#define H_DIM 16
#define D_DIM 64
#define KD    1024

#define NEG_BIG (-1e30f)

typedef short  short8  __attribute__((ext_vector_type(8)));
typedef short  short4v __attribute__((ext_vector_type(4)));
typedef float  f32x4   __attribute__((ext_vector_type(4)));

__device__ __forceinline__ float bf2f(short s) {
  return __uint_as_float(((unsigned)(unsigned short)s) << 16);
}
__device__ __forceinline__ short f2bf(float f) {
  unsigned u = __float_as_uint(f);
  u += 0x7fffu + ((u >> 16) & 1u);   // round-to-nearest-even
  return (short)(u >> 16);
}
__device__ __forceinline__ unsigned pk2(float lo, float hi) {
  return ((unsigned)(unsigned short)f2bf(lo)) | (((unsigned)(unsigned short)f2bf(hi)) << 16);
}

// Load an 8-element bf16 fragment from either bf16 or fp32 source (uniform flag).
__device__ __forceinline__ short8 ldfrag(const void* p, size_t off, int isf32) {
  if (isf32) {
    const float* q = (const float*)p + off;
    f32x4 lo = *(const f32x4*)q;
    f32x4 hi = *(const f32x4*)(q + 4);
    short8 r;
#pragma unroll
    for (int j = 0; j < 4; ++j) { r[j] = f2bf(lo[j]); r[j + 4] = f2bf(hi[j]); }
    return r;
  }
  return *(const short8*)((const short*)p + off);
}
__device__ __forceinline__ float ldbias(const void* b, int i, int isf32) {
  return isf32 ? ((const float*)b)[i] : bf2f(((const short*)b)[i]);
}

// ---------------------------------------------------------------------------
// Input-dtype probe (validated R5: correctly selected fp32).
// ---------------------------------------------------------------------------
__global__ void detect_k(const unsigned* __restrict__ q, unsigned* __restrict__ flag) {
  if (threadIdx.x == 0) {
    int c = 0;
    for (int i = 0; i < 256; ++i) {
      unsigned e = (q[i] >> 7) & 0xffu;
      c += (e >= 110u && e <= 135u) ? 1 : 0;
    }
    *flag = (c < 128) ? 1u : 0u;
  }
}

// ---------------------------------------------------------------------------
// LDS-staged GEMM, BM=BN=64, BK=32, 256 threads = 4 waves (wave tile 32x32).
// C[m][c] = sum_k X[m][k]*W[c][k] + bias[c].
// KIND=0: final projection. A = y (bf16 ws), out fp32 [m*1024+c]. Grid (32,16).
// KIND=1: fused QKV. m in [0,6144): src = m>>11 (q/k/v). out base += src*SZ.
//   q,k -> qp/kp [b,h,t,d] bf16 (TRANS epilogue); v -> vpt [b,h,d,t] (NORM).
// LDS rows padded 32->40 shorts: bank conflicts <=2-way (free, m136).
// Staging converts fp32->bf16 inline (flag), ws stays 16 MiB (known-safe).
// ---------------------------------------------------------------------------
#define LDSP 40
#define SZE  ((size_t)2 * T_DIM * C_DIM)

template<int KIND>
__global__ __launch_bounds__(256) void gemm2_k(const void* __restrict__ X0,
                                               const void* __restrict__ X1,
                                               const void* __restrict__ X2,
                                               const void* __restrict__ Wv,
                                               const void* __restrict__ Bv,
                                               void* __restrict__ outv,
                                               const unsigned* __restrict__ flagp)
{
  const unsigned f = flagp ? *flagp : 0u;
  const int wf = f ? 1 : 0;                 // weights/bias follow input dtype
  const int xf = (KIND == 1) ? wf : 0;      // KIND0 A-matrix is internal bf16

  const int tid  = threadIdx.x;
  const int lane = tid & 63;
  const int wave = tid >> 6;
  const int col16 = lane & 15;
  const int quad  = lane >> 4;
  const int wm = wave & 1;
  const int wn = wave >> 1;

  const int m0 = blockIdx.x * 64;
  const int c0 = blockIdx.y * 64;

  const void* Xv = X0;
  int arow = m0;
  bool isv = false;
  short* outb = (short*)outv;
  if (KIND == 1) {
    const int src = m0 >> 11;               // 0=q 1=k 2=v
    Xv = (src == 0) ? X0 : (src == 1) ? X1 : X2;
    arow = m0 & 2047;
    isv = (src == 2);
    outb = (short*)outv + (size_t)src * SZE;
  }

  __shared__ short As[64 * LDSP];
  __shared__ short Bs[64 * LDSP];

  const int srow = tid >> 2;                // staging row (0..63)
  const int sc8  = tid & 3;                 // 8-elem chunk within BK=32

  f32x4 acc[2][2] = {};                     // [i=m-sub][j=c-sub]

  for (int k0 = 0; k0 < KD; k0 += 32) {
    short8 va = ldfrag(Xv, (size_t)(arow + srow) * KD + k0 + sc8 * 8, xf);
    short8 vb = ldfrag(Wv, (size_t)(c0 + srow) * KD + k0 + sc8 * 8, wf);
    *(short8*)&As[srow * LDSP + sc8 * 8] = va;
    *(short8*)&Bs[srow * LDSP + sc8 * 8] = vb;
    __syncthreads();

    short8 fx[2], fw[2];
#pragma unroll
    for (int i = 0; i < 2; ++i)
      fx[i] = *(const short8*)&As[(wm * 32 + i * 16 + col16) * LDSP + quad * 8];
#pragma unroll
    for (int j = 0; j < 2; ++j)
      fw[j] = *(const short8*)&Bs[(wn * 32 + j * 16 + col16) * LDSP + quad * 8];

    if (KIND == 1 && isv) {
#pragma unroll
      for (int i = 0; i < 2; ++i)
#pragma unroll
        for (int j = 0; j < 2; ++j)
          acc[i][j] = __builtin_amdgcn_mfma_f32_16x16x32_bf16(fx[i], fw[j], acc[i][j], 0, 0, 0);
    } else {
#pragma unroll
      for (int i = 0; i < 2; ++i)
#pragma unroll
        for (int j = 0; j < 2; ++j)
          acc[i][j] = __builtin_amdgcn_mfma_f32_16x16x32_bf16(fw[j], fx[i], acc[i][j], 0, 0, 0);
    }
    __syncthreads();
  }

  if (KIND == 1 && isv) {
    // NORM: col=c(d), rows=m(t): 4 consecutive t -> vpt [b,h,d,t] (R5 MODE2)
#pragma unroll
    for (int i = 0; i < 2; ++i) {
#pragma unroll
      for (int j = 0; j < 2; ++j) {
        const int c  = c0 + wn * 32 + j * 16 + col16;
        const int t0 = arow + wm * 32 + i * 16 + quad * 4;
        const float bv = ldbias(Bv, c, wf);
        short4v pk;
#pragma unroll
        for (int r = 0; r < 4; ++r) pk[r] = f2bf(acc[i][j][r] + bv);
        const int bb = t0 >> 10, t = t0 & 1023, h = c >> 6, d = c & 63;
        size_t off = (size_t)((bb * H_DIM + h) * D_DIM + d) * T_DIM + t;
        *(short4v*)(outb + off) = pk;
      }
    }
  } else {
    // TRANS: col=m, rows=c (4 consecutive c)  (R5 MODE0/MODE1)
#pragma unroll
    for (int i = 0; i < 2; ++i) {
#pragma unroll
      for (int j = 0; j < 2; ++j) {
        const int m  = arow + wm * 32 + i * 16 + col16;
        const int cb = c0 + wn * 32 + j * 16 + quad * 4;
        if (KIND == 0) {
          f32x4 pv;
#pragma unroll
          for (int r = 0; r < 4; ++r) pv[r] = acc[i][j][r] + ldbias(Bv, cb + r, wf);
          *(f32x4*)((float*)outv + (size_t)m * C_DIM + cb) = pv;
        } else {
          short4v pk;
#pragma unroll
          for (int r = 0; r < 4; ++r) pk[r] = f2bf(acc[i][j][r] + ldbias(Bv, cb + r, wf));
          const int bb = m >> 10, t = m & 1023, h = cb >> 6, d = cb & 63;
          size_t off = ((size_t)(bb * H_DIM + h) << 16) + (size_t)t * D_DIM + d;
          *(short4v*)(outb + off) = pk;
        }
      }
    }
  }
}

// ---------------------------------------------------------------------------
// Causal flash attention, transposed-score formulation (verified R5).
// ---------------------------------------------------------------------------
__global__ __launch_bounds__(256) void attn_k(const short* __restrict__ qp,
                                              const short* __restrict__ kp,
                                              const short* __restrict__ vpt,
                                              short* __restrict__ y)
{
  const int lane = threadIdx.x & 63;
  const int wave = threadIdx.x >> 6;
  const int col  = lane & 15;
  const int quad = lane >> 4;
  const int bh = blockIdx.y;
  const int b = bh >> 4, h = bh & 15;
  const int qblk = (int)gridDim.x - 1 - (int)blockIdx.x;  // heavy blocks first
  const int q0 = qblk * 64 + wave * 16;
  const int myq = q0 + col;

  const short* qph = qp  + (size_t)bh * (T_DIM * D_DIM);
  const short* kph = kp  + (size_t)bh * (T_DIM * D_DIM);
  const short* vph = vpt + (size_t)bh * (D_DIM * T_DIM);

  short8 bQ[2];
#pragma unroll
  for (int kk = 0; kk < 2; ++kk)
    bQ[kk] = *(const short8*)(qph + (size_t)(q0 + col) * D_DIM + kk * 32 + quad * 8);

  f32x4 O[4] = {};
  float m_q = NEG_BIG, l_q = 0.0f;

  const int slA = col + ((quad & 1) * 32);
  const int slB = slA + 16;

  const int ktiles = (q0 + 47) >> 5;
  for (int kt = 0; kt < ktiles; ++kt) {
    const int kb = kt * 32;
    f32x4 st[2];
#pragma unroll
    for (int jt = 0; jt < 2; ++jt) {
      f32x4 s = {0.f, 0.f, 0.f, 0.f};
      const short* kbase = kph + (size_t)(kb + jt * 16 + col) * D_DIM + quad * 8;
      short8 aK0 = *(const short8*)(kbase);
      short8 aK1 = *(const short8*)(kbase + 32);
      s = __builtin_amdgcn_mfma_f32_16x16x32_bf16(aK0, bQ[0], s, 0, 0, 0);
      s = __builtin_amdgcn_mfma_f32_16x16x32_bf16(aK1, bQ[1], s, 0, 0, 0);
      st[jt] = s;
    }
    float mnew = m_q;
#pragma unroll
    for (int jt = 0; jt < 2; ++jt) {
#pragma unroll
      for (int r = 0; r < 4; ++r) {
        float sv = st[jt][r] * 0.125f;
        const int key = kb + jt * 16 + quad * 4 + r;
        sv = (key > myq) ? NEG_BIG : sv;
        st[jt][r] = sv;
        mnew = fmaxf(mnew, sv);
      }
    }
    mnew = fmaxf(mnew, __shfl_xor(mnew, 16));
    mnew = fmaxf(mnew, __shfl_xor(mnew, 32));
    const float alpha = __expf(m_q - mnew);
    m_q = mnew;
    float rs = 0.0f;
#pragma unroll
    for (int jt = 0; jt < 2; ++jt) {
#pragma unroll
      for (int r = 0; r < 4; ++r) {
        float p = __expf(st[jt][r] - mnew);
        st[jt][r] = p;
        rs += p;
      }
    }
    rs += __shfl_xor(rs, 16);
    rs += __shfl_xor(rs, 32);
    l_q = l_q * alpha + rs;
#pragma unroll
    for (int dt = 0; dt < 4; ++dt)
#pragma unroll
      for (int r = 0; r < 4; ++r) O[dt][r] *= alpha;

    const int a0 = (int)pk2(st[0][0], st[0][1]);
    const int a1 = (int)pk2(st[0][2], st[0][3]);
    const int b0 = (int)pk2(st[1][0], st[1][1]);
    const int b1 = (int)pk2(st[1][2], st[1][3]);
    const int tA0 = __shfl(a0, slA, 64), tB0 = __shfl(b0, slA, 64);
    const int tA1 = __shfl(a1, slA, 64), tB1 = __shfl(b1, slA, 64);
    const int tA2 = __shfl(a0, slB, 64), tB2 = __shfl(b0, slB, 64);
    const int tA3 = __shfl(a1, slB, 64), tB3 = __shfl(b1, slB, 64);
    union { unsigned u[4]; short8 s8; } uu;
    uu.u[0] = (unsigned)((quad < 2) ? tA0 : tB0);
    uu.u[1] = (unsigned)((quad < 2) ? tA1 : tB1);
    uu.u[2] = (unsigned)((quad < 2) ? tA2 : tB2);
    uu.u[3] = (unsigned)((quad < 2) ? tA3 : tB3);
    const short8 bP32 = uu.s8;

#pragma unroll
    for (int dt = 0; dt < 4; ++dt) {
      short8 aV = *(const short8*)(vph + (size_t)(dt * 16 + col) * T_DIM + kb + quad * 8);
      O[dt] = __builtin_amdgcn_mfma_f32_16x16x32_bf16(aV, bP32, O[dt], 0, 0, 0);
    }
  }

  const float rl = 1.0f / l_q;
  const int t = q0 + col;
  const size_t ybase = ((size_t)(b * T_DIM + t)) * C_DIM + h * D_DIM + quad * 4;
#pragma unroll
  for (int dt = 0; dt < 4; ++dt) {
    short4v pk;
#pragma unroll
    for (int r = 0; r < 4; ++r) pk[r] = f2bf(O[dt][r] * rl);
    *(short4v*)(y + ybase + dt * 16) = pk;
  }
}

// ---------------------------------------------------------------------------
extern "C" void kernel_launch(void* const* d_in, const int* in_sizes, int n_in,
                              void* d_out, int out_size, void* d_ws, size_t ws_size,
                              hipStream_t stream) {
  const void* q = d_in[0];
  const void* k = d_in[1];
  const void* v = d_in[2];
  int wi = (n_in >= 8 && in_sizes[4] == C_DIM * C_DIM) ? 4 : 3;
  const void* Wk = d_in[wi];
  const void* bk = d_in[wi + 1];
  const void* Wc = d_in[wi + 2];
  const void* bc = d_in[wi + 3];

  short* ws  = (short*)d_ws;
  short* qp  = ws;                 // [b,h,t,d] bf16
  short* kp  = ws + SZE;           // [b,h,t,d] bf16
  short* vpt = ws + 2 * SZE;       // [b,h,d,t] bf16
  short* y   = ws + 3 * SZE;       // [b,t,c]   bf16

  const size_t used = 4 * SZE * sizeof(short);   // 16 MiB (known-safe, R5)
  unsigned* flagp = (ws_size >= used + 64) ? (unsigned*)((char*)d_ws + used) : nullptr;
  if (flagp) detect_k<<<1, 64, 0, stream>>>((const unsigned*)q, flagp);

  dim3 blk(256);
  gemm2_k<1><<<dim3(96, 16), blk, 0, stream>>>(q, k, v, Wk, bk, qp, flagp);
  attn_k<<<dim3(16, 32), blk, 0, stream>>>(qp, kp, vpt, y);
  gemm2_k<0><<<dim3(32, 16), blk, 0, stream>>>(y, nullptr, nullptr, Wc, bc, d_out, flagp);
}